// Round 5
// baseline (2628.969 us; speedup 1.0000x reference)
//
#include <hip/hip_runtime.h>
#include <hip/hip_bf16.h>

// ---------------------------------------------------------------------------
// GraphS4mer forward, R9: 4-wave GRU blocks (2 col-tiles/wave) + 512-VGPR
// budget + asm-pinned register-resident weights + LDS-only step barrier.
//   R8 post-mortem: additive step = LDS ~750 (8 waves x 8KB duplicated
//   h-tile reads at 85 B/cyc) + MFMA ~390 + VALU ~850 (incl. weight-reload
//   addr: VGPR_Count=128 < 156-reg weight set -> compiler remats ~25 global
//   loads/step; FETCH 79MB = 2x xb). Restructure: 4 waves x 64 lanes, each
//   wave owns col-tiles {16w, 64+16w}. LDS reads halve (32KB/step); at
//   waves_per_eu(1,1) budget=512 VGPR, the 312-VGPR doubled weight set is
//   pinned via asm volatile("+v") -> no remat, no reloads. MFMA/VALU per
//   SIMD unchanged (2 tiles x 1/2 waves). Chain accumulation order kept
//   bitwise identical to R8.
// ---------------------------------------------------------------------------

#define NSEQ   304
#define TT     2048
#define HH     128
#define NNODE  19
#define NDYN   8
#define NGRAPH 128
#define NBLK   76             // 4 blocks per 16-seq group, q-split

typedef __bf16 bf16x8 __attribute__((ext_vector_type(8)));
typedef float  f32x4  __attribute__((ext_vector_type(4)));

static __device__ __forceinline__ f32x4 mfma16(bf16x8 a, bf16x8 b, f32x4 c) {
  return __builtin_amdgcn_mfma_f32_16x16x32_bf16(a, b, c, 0, 0, 0);
}

// GRU gate update: r=sig(cr+Br), z=sig(cz+Bz), n=tanh(cn+bin + r*(cm+bhn)),
// h = n + z*(hp-n).  nBr/nBz are -log2(e)*(bih+bhh) prefolded.
static __device__ __forceinline__ float gate_step(
    float cr, float cz, float cn, float cm,
    float nBr, float nBz, float bin, float bhn, float hp)
{
  const float er = __builtin_amdgcn_exp2f(__builtin_fmaf(cr, -1.4426950408889634f, nBr));
  const float ez = __builtin_amdgcn_exp2f(__builtin_fmaf(cz, -1.4426950408889634f, nBz));
  const float r  = __builtin_amdgcn_rcpf(1.f + er);
  const float z  = __builtin_amdgcn_rcpf(1.f + ez);
  const float gn = __builtin_fmaf(r, cm + bhn, cn + bin);
  const float en = __builtin_amdgcn_exp2f(gn * 2.8853900817779268f);   // e^(2gn)
  const float nn = __builtin_fmaf(__builtin_amdgcn_rcpf(1.f + en), -2.f, 1.f);
  return __builtin_fmaf(z, hp - nn, nn);
}

// ---------------------------------------------------------------------------
// Prep: weights -> bf16 fragment order. dst[((w*3+gs)*nk+kc)*64+l][8] =
//   src[(128*gs+16*w+(l&15))*K + kc*32 + (l>>4)*8 + u]
// ---------------------------------------------------------------------------
__global__ void wprep_kernel(const float* __restrict__ src, __bf16* __restrict__ dst,
                             int K, int nk)
{
  const int i = blockIdx.x * 256 + threadIdx.x;
  const int total = 8 * 3 * nk * 64;
  if (i >= total) return;
  const int l = i & 63;
  int rest = i >> 6;
  const int kc = rest % nk; rest /= nk;
  const int gs = rest % 3;
  const int w  = rest / 3;
  const int row = 128 * gs + 16 * w + (l & 15);
  const float* s = src + (size_t)row * K + kc * 32 + (l >> 4) * 8;
  bf16x8 v;
  #pragma unroll
  for (int u = 0; u < 8; ++u) v[u] = (__bf16)s[u];
  *(bf16x8*)&dst[(size_t)i * 8] = v;
}

// x -> bf16 A-fragment layout: xb[((g*TT+t)*64+l)*8+u] =
//   x[(g*16+(l&15))*TT*32 + t*32 + (l>>4)*8 + u]
__global__ void xprep_kernel(const float* __restrict__ x, __bf16* __restrict__ xb)
{
  const int i = blockIdx.x * 256 + threadIdx.x;
  if (i >= NNODE * TT * 64) return;
  const int l = i & 63;
  const int t = (i >> 6) & (TT - 1);
  const int g = i >> 17;                       // 64*2048 = 2^17
  const float* s = x + ((size_t)(g * 16 + (l & 15)) * TT + t) * 32 + (l >> 4) * 8;
  bf16x8 v;
  #pragma unroll
  for (int u = 0; u < 8; ++u) v[u] = (__bf16)s[u];
  *(bf16x8*)&xb[(size_t)i * 8] = v;
}

// ---------------------------------------------------------------------------
// LDS-only step barrier (R8-verified): ds ops retired before s_barrier;
// vmcnt NOT drained -> x prefetch rides across steps.
// ---------------------------------------------------------------------------
#define STEP_BARRIER() do {                                          \
    asm volatile("s_waitcnt lgkmcnt(0)" ::: "memory");               \
    __builtin_amdgcn_s_barrier();                                    \
    __builtin_amdgcn_sched_barrier(0);                               \
  } while (0)

// ---------------------------------------------------------------------------
// Templated GRU body: Q0 = owned acc-row slot (block-uniform).
// 4 waves x 64 lanes; wave w owns col-tiles c=0 -> cols [16w,16w+16) and
// c=1 -> cols [64+16w, 64+16w+16).
// h-LDS layout: row r (16 rows), 128 bf16/row = 16 x 16B blocks; block b
// stored at blk' = b ^ (r&7) (swizzle kept from R6).
// ---------------------------------------------------------------------------
template<int Q0>
static __device__ __forceinline__ void gru_body(
    const __bf16* __restrict__ xb,
    const __bf16* __restrict__ wI0, const __bf16* __restrict__ wH0,
    const __bf16* __restrict__ wI1, const __bf16* __restrict__ wH1,
    const float* __restrict__ bih0, const float* __restrict__ bhh0,
    const float* __restrict__ bih1, const float* __restrict__ bhh1,
    float* __restrict__ xg,
    __bf16* s0a, __bf16* s0b, __bf16* s1a, __bf16* s1b, int gg)
{
  const int tid = threadIdx.x;
  const int w   = tid >> 6;           // wave 0..3
  const int l   = tid & 63;
  const int lm  = l & 15;
  const int lq  = l >> 4;
  const f32x4 z4 = {0.f, 0.f, 0.f, 0.f};

  // ---- weights: 2 col-tiles per wave, bf16 fragments, register-resident ----
  bf16x8 bI0[2][3], bH0[2][3][4], bI1[2][3][4], bH1[2][3][4];
  #pragma unroll
  for (int c = 0; c < 2; ++c) {
    const int wb = w + 4 * c;         // 16-col block index 0..7
    #pragma unroll
    for (int gs = 0; gs < 3; ++gs)
      bI0[c][gs] = *(const bf16x8*)&wI0[(size_t)((wb * 3 + gs) * 64 + l) * 8];
    #pragma unroll
    for (int gs = 0; gs < 3; ++gs)
      #pragma unroll
      for (int kc = 0; kc < 4; ++kc) {
        const size_t fi = (size_t)(((wb * 3 + gs) * 4 + kc) * 64 + l) * 8;
        bH0[c][gs][kc] = *(const bf16x8*)&wH0[fi];
        bI1[c][gs][kc] = *(const bf16x8*)&wI1[fi];
        bH1[c][gs][kc] = *(const bf16x8*)&wH1[fi];
      }
  }
  // Pin every fragment: value now originates from inline asm -> cannot be
  // rematerialized as a global reload; must stay register-resident.
  #pragma unroll
  for (int c = 0; c < 2; ++c)
    #pragma unroll
    for (int gs = 0; gs < 3; ++gs) {
      asm volatile("" : "+v"(bI0[c][gs]));
      #pragma unroll
      for (int kc = 0; kc < 4; ++kc) {
        asm volatile("" : "+v"(bH0[c][gs][kc]));
        asm volatile("" : "+v"(bI1[c][gs][kc]));
        asm volatile("" : "+v"(bH1[c][gs][kc]));
      }
    }

  const float L2E = 1.4426950408889634f;
  int jc[2];
  float nBr0[2], nBz0[2], bin0[2], bhn0[2], nBr1[2], nBz1[2], bin1[2], bhn1[2];
  #pragma unroll
  for (int c = 0; c < 2; ++c) {
    const int j = 16 * w + lm + 64 * c;
    jc[c] = j;
    nBr0[c] = -L2E * (bih0[j] + bhh0[j]);
    nBz0[c] = -L2E * (bih0[128 + j] + bhh0[128 + j]);
    bin0[c] = bih0[256 + j]; bhn0[c] = bhh0[256 + j];
    nBr1[c] = -L2E * (bih1[j] + bhh1[j]);
    nBz1[c] = -L2E * (bih1[128 + j] + bhh1[128 + j]);
    bin1[c] = bih1[256 + j]; bhn1[c] = bhh1[256 + j];
  }

  for (int i = tid; i < 16 * HH; i += 256) {
    s0a[i] = (__bf16)0.f; s0b[i] = (__bf16)0.f;
    s1a[i] = (__bf16)0.f; s1b[i] = (__bf16)0.f;
  }

  // ---- swizzled read offsets (elements): row lm, 16B block (kc*4+lq)^(lm&7)
  const int sw = lm & 7;
  int eo[4];
  #pragma unroll
  for (int kc = 0; kc < 4; ++kc)
    eo[kc] = lm * HH + ((((kc << 2) | lq) ^ sw) << 3);

  // ---- owned row / write offsets / output indexing (fixed per thread)
  const int myrow = lq * 4 + Q0;
  int woff[2];
  #pragma unroll
  for (int c = 0; c < 2; ++c)
    woff[c] = myrow * HH + (((jc[c] >> 3) ^ (myrow & 7)) << 3) + (jc[c] & 7);
  const int seq   = gg * 16 + myrow;
  const int bidx  = seq / NNODE;
  const int node  = seq - bidx * NNODE;

  float h0p[2] = {0.f, 0.f}, h1p[2] = {0.f, 0.f}, hsum[2] = {0.f, 0.f};

  const __bf16* xrow = xb + (size_t)gg * TT * 512 + l * 8;
  bf16x8 a0 = *(const bf16x8*)xrow;          // t = 0 fragment
  __syncthreads();                           // init visible (full drain once)

  for (int t = 0; t < TT; ++t) {
    __bf16*       h0w = (t & 1) ? s0b : s0a;   // h0_t
    const __bf16* h0r = (t & 1) ? s0a : s0b;   // h0_{t-1}
    __bf16*       h1w = (t & 1) ? s1a : s1b;   // h1_{t-1}
    const __bf16* h1r = (t & 1) ? s1b : s1a;   // h1_{t-2}

    // prefetch next-step x fragment FIRST: rides across the step barrier.
    bf16x8 a0n = *(const bf16x8*)(xrow + (size_t)((t + 1) & (TT - 1)) * 512);

    bf16x8 ah0[4], ah1[4];
    #pragma unroll
    for (int kc = 0; kc < 4; ++kc) ah0[kc] = *(const bf16x8*)&h0r[eo[kc]];
    #pragma unroll
    for (int kc = 0; kc < 4; ++kc) ah1[kc] = *(const bf16x8*)&h1r[eo[kc]];

    // ---- L0 x-part first: no LDS dependence
    f32x4 Cr[2], Cz[2], Cn[2], Cm[2], Dr[2], Dz[2], Dn[2], Dm[2];
    #pragma unroll
    for (int c = 0; c < 2; ++c) {
      Cr[c] = mfma16(a0, bI0[c][0], z4);
      Cz[c] = mfma16(a0, bI0[c][1], z4);
      Cn[c] = mfma16(a0, bI0[c][2], z4);
      Cm[c] = z4; Dr[c] = z4; Dz[c] = z4; Dn[c] = z4; Dm[c] = z4;
    }

    // ---- L1 MFMAs (step t-1): per-acc order identical to R8
    if (t > 0) {
      #pragma unroll
      for (int kc = 0; kc < 4; ++kc)
        #pragma unroll
        for (int c = 0; c < 2; ++c) {
          Dr[c] = mfma16(ah0[kc], bI1[c][0][kc], Dr[c]);
          Dz[c] = mfma16(ah0[kc], bI1[c][1][kc], Dz[c]);
          Dn[c] = mfma16(ah0[kc], bI1[c][2][kc], Dn[c]);
        }
      #pragma unroll
      for (int kc = 0; kc < 4; ++kc)
        #pragma unroll
        for (int c = 0; c < 2; ++c) {
          Dr[c] = mfma16(ah1[kc], bH1[c][0][kc], Dr[c]);
          Dz[c] = mfma16(ah1[kc], bH1[c][1][kc], Dz[c]);
          Dm[c] = mfma16(ah1[kc], bH1[c][2][kc], Dm[c]);
        }
    }

    // ---- L0 h-part
    #pragma unroll
    for (int kc = 0; kc < 4; ++kc)
      #pragma unroll
      for (int c = 0; c < 2; ++c) {
        Cr[c] = mfma16(ah0[kc], bH0[c][0][kc], Cr[c]);
        Cz[c] = mfma16(ah0[kc], bH0[c][1][kc], Cz[c]);
        Cm[c] = mfma16(ah0[kc], bH0[c][2][kc], Cm[c]);
      }

    // ---- L1 gates first
    if (t > 0) {
      #pragma unroll
      for (int c = 0; c < 2; ++c) {
        const float h = gate_step(Dr[c][Q0], Dz[c][Q0], Dn[c][Q0], Dm[c][Q0],
                                  nBr1[c], nBz1[c], bin1[c], bhn1[c], h1p[c]);
        h1p[c] = h;
        hsum[c] += h;
        h1w[woff[c]] = (__bf16)h;
      }
      const int s = t - 1;
      if ((s & 255) == 255) {
        const int win = s >> 8;
        #pragma unroll
        for (int c = 0; c < 2; ++c) {
          xg[((size_t)(bidx * NDYN + win) * NNODE + node) * HH + jc[c]] =
              hsum[c] * (1.f / 256.f);
          hsum[c] = 0.f;
        }
      }
    }
    // ---- L0 gates
    #pragma unroll
    for (int c = 0; c < 2; ++c) {
      const float h = gate_step(Cr[c][Q0], Cz[c][Q0], Cn[c][Q0], Cm[c][Q0],
                                nBr0[c], nBz0[c], bin0[c], bhn0[c], h0p[c]);
      h0p[c] = h;
      h0w[woff[c]] = (__bf16)h;
    }
    a0 = a0n;
    STEP_BARRIER();
  }

  // ---- epilogue: L1 step 2047 (h0_2047 in s0b, h1_2046 in s1a)
  {
    const __bf16* h0r = s0b;
    const __bf16* h1r = s1a;
    bf16x8 ah0[4], ah1[4];
    #pragma unroll
    for (int kc = 0; kc < 4; ++kc) ah0[kc] = *(const bf16x8*)&h0r[eo[kc]];
    #pragma unroll
    for (int kc = 0; kc < 4; ++kc) ah1[kc] = *(const bf16x8*)&h1r[eo[kc]];
    f32x4 Dr[2], Dz[2], Dn[2], Dm[2];
    #pragma unroll
    for (int c = 0; c < 2; ++c) { Dr[c] = z4; Dz[c] = z4; Dn[c] = z4; Dm[c] = z4; }
    #pragma unroll
    for (int kc = 0; kc < 4; ++kc)
      #pragma unroll
      for (int c = 0; c < 2; ++c) {
        Dr[c] = mfma16(ah0[kc], bI1[c][0][kc], Dr[c]);
        Dz[c] = mfma16(ah0[kc], bI1[c][1][kc], Dz[c]);
        Dn[c] = mfma16(ah0[kc], bI1[c][2][kc], Dn[c]);
      }
    #pragma unroll
    for (int kc = 0; kc < 4; ++kc)
      #pragma unroll
      for (int c = 0; c < 2; ++c) {
        Dr[c] = mfma16(ah1[kc], bH1[c][0][kc], Dr[c]);
        Dz[c] = mfma16(ah1[kc], bH1[c][1][kc], Dz[c]);
        Dm[c] = mfma16(ah1[kc], bH1[c][2][kc], Dm[c]);
      }
    #pragma unroll
    for (int c = 0; c < 2; ++c) {
      const float h = gate_step(Dr[c][Q0], Dz[c][Q0], Dn[c][Q0], Dm[c][Q0],
                                nBr1[c], nBz1[c], bin1[c], bhn1[c], h1p[c]);
      hsum[c] += h;
      xg[((size_t)(bidx * NDYN + 7) * NNODE + node) * HH + jc[c]] =
          hsum[c] * (1.f / 256.f);
    }
  }
}

__global__ __launch_bounds__(256, 1) __attribute__((amdgpu_waves_per_eu(1, 1)))
void gru2_kernel(
    const __bf16* __restrict__ xb,
    const __bf16* __restrict__ wI0, const __bf16* __restrict__ wH0,
    const __bf16* __restrict__ wI1, const __bf16* __restrict__ wH1,
    const float* __restrict__ bih0, const float* __restrict__ bhh0,
    const float* __restrict__ bih1, const float* __restrict__ bhh1,
    float* __restrict__ xg)
{
  __shared__ __align__(16) __bf16 sH0[2][16 * HH];
  __shared__ __align__(16) __bf16 sH1[2][16 * HH];
  const int gg = blockIdx.x >> 2;
  switch (blockIdx.x & 3) {
    case 0: gru_body<0>(xb, wI0, wH0, wI1, wH1, bih0, bhh0, bih1, bhh1, xg,
                        sH0[0], sH0[1], sH1[0], sH1[1], gg); break;
    case 1: gru_body<1>(xb, wI0, wH0, wI1, wH1, bih0, bhh0, bih1, bhh1, xg,
                        sH0[0], sH0[1], sH1[0], sH1[1], gg); break;
    case 2: gru_body<2>(xb, wI0, wH0, wI1, wH1, bih0, bhh0, bih1, bhh1, xg,
                        sH0[0], sH0[1], sH1[0], sH1[1], gg); break;
    default: gru_body<3>(xb, wI0, wH0, wI1, wH1, bih0, bhh0, bih1, bhh1, xg,
                         sH0[0], sH0[1], sH1[0], sH1[1], gg); break;
  }
}

// ---------------------------------------------------------------------------
// Per-graph stage (unchanged — verified, negligible time).
// ---------------------------------------------------------------------------
static __device__ __forceinline__ float blockReduce256(float v, float* sRed)
{
  const int tid = threadIdx.x;
  __syncthreads();
  sRed[tid] = v;
  __syncthreads();
  #pragma unroll
  for (int st = 128; st >= 1; st >>= 1) {
    if (tid < st) sRed[tid] += sRed[tid + st];
    __syncthreads();
  }
  return sRed[0];
}

__global__ __launch_bounds__(256) void graph_kernel(
    const float* __restrict__ xg,
    const float* __restrict__ Wq, const float* __restrict__ Wk,
    const float* __restrict__ Wl, const float* __restrict__ Wr,
    const float* __restrict__ bs, const float* __restrict__ Wc,
    float* __restrict__ out)
{
  const int tid = threadIdx.x;
  const int bp = blockIdx.x;

  __shared__ float sX[NNODE * HH];
  __shared__ float sQ[NNODE * HH];
  __shared__ float sK[NNODE * HH];
  __shared__ float sG[NNODE * NNODE];
  __shared__ float sA[NNODE * NNODE];
  __shared__ float sS[NNODE * NNODE];
  __shared__ float sNorm[NNODE];
  __shared__ float sDis[NNODE];
  __shared__ float sDeg[NNODE];
  __shared__ float sThr;
  __shared__ float sRed[256];

  for (int idx = tid; idx < NNODE * HH; idx += 256)
    sX[idx] = xg[(size_t)bp * NNODE * HH + idx];
  __syncthreads();

  if (tid < NNODE) {
    float acc = 0.f;
    const float* xv = &sX[tid * HH];
    #pragma unroll 4
    for (int d = 0; d < HH; ++d) acc += xv[d] * xv[d];
    sNorm[tid] = 1.f / sqrtf(acc);
  }
  for (int e = tid; e < NNODE * NNODE; e += 256) {
    const int n = e / NNODE, m = e % NNODE;
    float acc = 0.f;
    const float* a = &sX[n * HH];
    const float* b = &sX[m * HH];
    #pragma unroll 4
    for (int d = 0; d < HH; ++d) acc += a[d] * b[d];
    sG[e] = acc;
  }
  for (int e = tid; e < NNODE * NNODE; e += 256) sA[e] = 0.f;
  __syncthreads();

  if (tid < NNODE) {
    const int r = tid;
    const float nr = sNorm[r];
    float v0 = -1e30f, v1 = -1e30f, v2 = -1e30f;
    int i0 = 0, i1 = 0, i2 = 0;
    for (int m = 0; m < NNODE; ++m) {
      const float v = sG[r * NNODE + m] * nr * sNorm[m];
      if (v > v0)      { v2 = v1; i2 = i1; v1 = v0; i1 = i0; v0 = v; i0 = m; }
      else if (v > v1) { v2 = v1; i2 = i1; v1 = v;  i1 = m; }
      else if (v > v2) { v2 = v;  i2 = m; }
    }
    sA[r * NNODE + i0] = fmaxf(v0, 0.f);
    sA[r * NNODE + i1] = fmaxf(v1, 0.f);
    sA[r * NNODE + i2] = fmaxf(v2, 0.f);
  }
  __syncthreads();

  {
    float t0 = 0.f, t1 = 0.f;
    if (tid < 361) {
      const int n = tid / NNODE, m = tid % NNODE;
      t0 = (n == m) ? 1.f : 0.5f * (sA[n * NNODE + m] + sA[m * NNODE + n]);
    }
    if (tid + 256 < 361) {
      const int e = tid + 256;
      const int n = e / NNODE, m = e % NNODE;
      t1 = (n == m) ? 1.f : 0.5f * (sA[n * NNODE + m] + sA[m * NNODE + n]);
    }
    __syncthreads();
    if (tid < 361) sA[tid] = t0;
    if (tid + 256 < 361) sA[tid + 256] = t1;
  }

  for (int o = tid; o < NNODE * HH; o += 256) {
    const int n = o >> 7, hh = o & 127;
    float aq = 0.f, ak = 0.f;
    const float* xv = &sX[n * HH];
    const float* wq = &Wq[hh * HH];
    const float* wk = &Wk[hh * HH];
    #pragma unroll 4
    for (int d = 0; d < HH; ++d) { const float xx = xv[d]; aq += xx * wq[d]; ak += xx * wk[d]; }
    sQ[o] = aq; sK[o] = ak;
  }
  __syncthreads();

  for (int e = tid; e < NNODE * NNODE; e += 256) {
    const int n = e / NNODE, m = e % NNODE;
    float acc = 0.f;
    const float* a = &sQ[n * HH];
    const float* b = &sK[m * HH];
    #pragma unroll 4
    for (int d = 0; d < HH; ++d) acc += a[d] * b[d];
    sS[e] = acc * 0.08838834764831845f;
  }
  __syncthreads();
  if (tid < NNODE) {
    const int r = tid;
    float mx = -1e30f;
    for (int m = 0; m < NNODE; ++m) mx = fmaxf(mx, sS[r * NNODE + m]);
    float sum = 0.f;
    for (int m = 0; m < NNODE; ++m) sum += expf(sS[r * NNODE + m] - mx);
    const float inv = 1.f / sum;
    for (int m = 0; m < NNODE; ++m)
      sS[r * NNODE + m] = expf(sS[r * NNODE + m] - mx) * inv;
  }
  __syncthreads();

  for (int e = tid; e < NNODE * NNODE; e += 256) {
    const int n = e / NNODE, m = e % NNODE;
    sA[e] = 0.1f * sA[e] + 0.45f * (sS[n * NNODE + m] + sS[m * NNODE + n]);
  }
  __syncthreads();

  for (int e = tid; e < NNODE * NNODE; e += 256) {
    const float v = sA[e];
    int cg = 0, ce = 0;
    for (int f = 0; f < NNODE * NNODE; ++f) {
      const float u = sA[f];
      cg += (u > v);
      ce += (u == v);
    }
    if (cg <= 180 && cg + ce > 180) sThr = v;
  }
  __syncthreads();
  {
    const float thr = sThr;
    for (int e = tid; e < NNODE * NNODE; e += 256)
      sA[e] = (sA[e] > thr) ? sA[e] : 0.f;
  }
  __syncthreads();

  if (tid < NNODE) {
    const int r = tid;
    float dsum = 0.f;
    int cnt = 0;
    for (int m = 0; m < NNODE; ++m) {
      const float v = sA[r * NNODE + m];
      dsum += v;
      if (m != r && v > 0.f) ++cnt;
    }
    sDis[r] = (dsum > 0.f) ? 1.f / sqrtf(dsum) : 0.f;
    sDeg[r] = (float)(cnt < 1 ? 1 : cnt);
  }
  __syncthreads();

  float regp = 0.f;
  for (int e = tid; e < NNODE * NNODE; e += 256) {
    const int n = e / NNODE, m = e % NNODE;
    const float Lnm = ((n == m) ? 1.f : 0.f) - sDis[n] * sDis[m] * sA[e];
    regp += Lnm * sG[e];
  }
  {
    const float tr = blockReduce256(regp, sRed);
    if (tid == 0)
      atomicAdd(out + 16, tr * (1.f / (16384.f * (float)NGRAPH)));
  }
  __syncthreads();

  for (int o = tid; o < NNODE * HH; o += 256) {
    const int n = o >> 7, d = o & 127;
    float acc = 0.f;
    for (int m = 0; m < NNODE; ++m)
      if (m != n && sA[n * NNODE + m] > 0.f) acc += sX[m * HH + d];
    sQ[o] = acc / sDeg[n];
  }
  __syncthreads();

  float lgp = 0.f;
  for (int o = tid; o < NNODE * HH; o += 256) {
    const int n = o >> 7, hh = o & 127;
    float acc = bs[hh];
    const float* av = &sQ[n * HH];
    const float* xv = &sX[n * HH];
    const float* wl = &Wl[hh * HH];
    const float* wr = &Wr[hh * HH];
    #pragma unroll 4
    for (int d = 0; d < HH; ++d) acc += av[d] * wl[d] + xv[d] * wr[d];
    lgp += fmaxf(acc, 0.f) * Wc[hh];
  }
  {
    const float tot = blockReduce256(lgp, sRed);
    if (tid == 0)
      atomicAdd(out + (bp >> 3), tot * 0.125f);
  }
}

__global__ void init_out_kernel(float* __restrict__ out, const float* __restrict__ bc)
{
  const int i = threadIdx.x;
  if (i < 16) out[i] = bc[0];
  else if (i == 16) out[16] = 0.f;
}

// ---------------------------------------------------------------------------
extern "C" void kernel_launch(void* const* d_in, const int* in_sizes, int n_in,
                              void* d_out, int out_size, void* d_ws, size_t ws_size,
                              hipStream_t stream)
{
  const float* x    = (const float*)d_in[0];
  const float* Wih0 = (const float*)d_in[1];
  const float* Whh0 = (const float*)d_in[2];
  const float* bih0 = (const float*)d_in[3];
  const float* bhh0 = (const float*)d_in[4];
  const float* Wih1 = (const float*)d_in[5];
  const float* Whh1 = (const float*)d_in[6];
  const float* bih1 = (const float*)d_in[7];
  const float* bhh1 = (const float*)d_in[8];
  const float* Wq   = (const float*)d_in[9];
  const float* Wk   = (const float*)d_in[10];
  const float* Wl   = (const float*)d_in[11];
  const float* Wr   = (const float*)d_in[12];
  const float* bsg  = (const float*)d_in[13];
  const float* Wc   = (const float*)d_in[14];
  const float* bc   = (const float*)d_in[15];
  float* out = (float*)d_out;

  // workspace layout
  const size_t XB  = (size_t)NNODE * TT * 512 * sizeof(__bf16);  // 39.8 MB
  const size_t WI0 = (size_t)8 * 3 * 64 * 8 * sizeof(__bf16);    // 24 KB
  const size_t WH  = (size_t)8 * 3 * 4 * 64 * 8 * sizeof(__bf16);// 96 KB
  char* p = (char*)d_ws;
  __bf16* xb  = (__bf16*)p;            p += XB;
  __bf16* wI0 = (__bf16*)p;            p += WI0;
  __bf16* wH0 = (__bf16*)p;            p += WH;
  __bf16* wI1 = (__bf16*)p;            p += WH;
  __bf16* wH1 = (__bf16*)p;            p += WH;
  float*  xg  = (float*)p;

  init_out_kernel<<<1, 64, 0, stream>>>(out, bc);
  wprep_kernel<<<6, 256, 0, stream>>>(Wih0, wI0, 32, 1);
  wprep_kernel<<<24, 256, 0, stream>>>(Whh0, wH0, 128, 4);
  wprep_kernel<<<24, 256, 0, stream>>>(Whh1, wH1, 128, 4);
  wprep_kernel<<<24, 256, 0, stream>>>(Wih1, wI1, 128, 4);
  xprep_kernel<<<(NNODE * TT * 64 + 255) / 256, 256, 0, stream>>>(x, xb);
  gru2_kernel<<<NBLK, 256, 0, stream>>>(
      xb, wI0, wH0, wI1, wH1, bih0, bhh0, bih1, bhh1, xg);
  graph_kernel<<<NGRAPH, 256, 0, stream>>>(xg, Wq, Wk, Wl, Wr, bsg, Wc, out);
}

// Round 6
// 2024.538 us; speedup vs baseline: 1.2986x; 1.2986x over previous
//
#include <hip/hip_runtime.h>
#include <hip/hip_bf16.h>

// ---------------------------------------------------------------------------
// GraphS4mer forward, R10: R8 structure (8 waves, 1 col-tile/wave, q-split,
// LDS-only barrier) + asm-PINNED register-resident weights at 2 waves/SIMD.
//   R9 post-mortem: pins at waves_per_eu(1,1) halved bank-conflicts as
//   predicted but lost TLP (1 wave/SIMD) and pushed weights into AGPRs with
//   v_accvgpr traffic -> net regression. The un-tested cell is pins WITH
//   2 waves/SIMD: R8's allocator chose 128 VGPR (< 156-VGPR weight set) and
//   remats ~28 fragment loads per step (invisible in FETCH: L2 hits) -- the
//   candidate for R8's unexplained ~845 cyc/SIMD/step VALU term. Weight set
//   156 + state ~95 = ~250 <= 256 budget at 2 waves/EU, so pinning must not
//   cost occupancy. Everything else identical to R8.
// ---------------------------------------------------------------------------

#define NSEQ   304
#define TT     2048
#define HH     128
#define NNODE  19
#define NDYN   8
#define NGRAPH 128
#define NBLK   76             // 4 blocks per 16-seq group, q-split

typedef __bf16 bf16x8 __attribute__((ext_vector_type(8)));
typedef float  f32x4  __attribute__((ext_vector_type(4)));

static __device__ __forceinline__ f32x4 mfma16(bf16x8 a, bf16x8 b, f32x4 c) {
  return __builtin_amdgcn_mfma_f32_16x16x32_bf16(a, b, c, 0, 0, 0);
}

// GRU gate update: r=sig(cr+Br), z=sig(cz+Bz), n=tanh(cn+bin + r*(cm+bhn)),
// h = n + z*(hp-n).  nBr/nBz are -log2(e)*(bih+bhh) prefolded.
static __device__ __forceinline__ float gate_step(
    float cr, float cz, float cn, float cm,
    float nBr, float nBz, float bin, float bhn, float hp)
{
  const float er = __builtin_amdgcn_exp2f(__builtin_fmaf(cr, -1.4426950408889634f, nBr));
  const float ez = __builtin_amdgcn_exp2f(__builtin_fmaf(cz, -1.4426950408889634f, nBz));
  const float r  = __builtin_amdgcn_rcpf(1.f + er);
  const float z  = __builtin_amdgcn_rcpf(1.f + ez);
  const float gn = __builtin_fmaf(r, cm + bhn, cn + bin);
  const float en = __builtin_amdgcn_exp2f(gn * 2.8853900817779268f);   // e^(2gn)
  const float nn = __builtin_fmaf(__builtin_amdgcn_rcpf(1.f + en), -2.f, 1.f);
  return __builtin_fmaf(z, hp - nn, nn);
}

// ---------------------------------------------------------------------------
// Prep: weights -> bf16 fragment order. dst[((w*3+gs)*nk+kc)*64+l][8] =
//   src[(128*gs+16*w+(l&15))*K + kc*32 + (l>>4)*8 + u]
// ---------------------------------------------------------------------------
__global__ void wprep_kernel(const float* __restrict__ src, __bf16* __restrict__ dst,
                             int K, int nk)
{
  const int i = blockIdx.x * 256 + threadIdx.x;
  const int total = 8 * 3 * nk * 64;
  if (i >= total) return;
  const int l = i & 63;
  int rest = i >> 6;
  const int kc = rest % nk; rest /= nk;
  const int gs = rest % 3;
  const int w  = rest / 3;
  const int row = 128 * gs + 16 * w + (l & 15);
  const float* s = src + (size_t)row * K + kc * 32 + (l >> 4) * 8;
  bf16x8 v;
  #pragma unroll
  for (int u = 0; u < 8; ++u) v[u] = (__bf16)s[u];
  *(bf16x8*)&dst[(size_t)i * 8] = v;
}

// x -> bf16 A-fragment layout: xb[((g*TT+t)*64+l)*8+u] =
//   x[(g*16+(l&15))*TT*32 + t*32 + (l>>4)*8 + u]
__global__ void xprep_kernel(const float* __restrict__ x, __bf16* __restrict__ xb)
{
  const int i = blockIdx.x * 256 + threadIdx.x;
  if (i >= NNODE * TT * 64) return;
  const int l = i & 63;
  const int t = (i >> 6) & (TT - 1);
  const int g = i >> 17;                       // 64*2048 = 2^17
  const float* s = x + ((size_t)(g * 16 + (l & 15)) * TT + t) * 32 + (l >> 4) * 8;
  bf16x8 v;
  #pragma unroll
  for (int u = 0; u < 8; ++u) v[u] = (__bf16)s[u];
  *(bf16x8*)&xb[(size_t)i * 8] = v;
}

// ---------------------------------------------------------------------------
// LDS-only step barrier (R8-verified): ds ops retired before s_barrier;
// vmcnt NOT drained -> x prefetch rides across steps.
// ---------------------------------------------------------------------------
#define STEP_BARRIER() do {                                          \
    asm volatile("s_waitcnt lgkmcnt(0)" ::: "memory");               \
    __builtin_amdgcn_s_barrier();                                    \
    __builtin_amdgcn_sched_barrier(0);                               \
  } while (0)

// ---------------------------------------------------------------------------
// Templated GRU body: Q0 = owned acc-row slot (block-uniform).
// h-LDS layout: row r (16 rows), 128 bf16/row = 16 x 16B blocks; block b is
// stored at blk' = b ^ (r&7).
// ---------------------------------------------------------------------------
template<int Q0>
static __device__ __forceinline__ void gru_body(
    const __bf16* __restrict__ xb,
    const __bf16* __restrict__ wI0, const __bf16* __restrict__ wH0,
    const __bf16* __restrict__ wI1, const __bf16* __restrict__ wH1,
    const float* __restrict__ bih0, const float* __restrict__ bhh0,
    const float* __restrict__ bih1, const float* __restrict__ bhh1,
    float* __restrict__ xg,
    __bf16* s0a, __bf16* s0b, __bf16* s1a, __bf16* s1b, int gg)
{
  const int tid = threadIdx.x;
  const int w   = tid >> 6;
  const int l   = tid & 63;
  const int lm  = l & 15;
  const int lq  = l >> 4;
  const int j   = 16 * w + lm;
  const f32x4 z4 = {0.f, 0.f, 0.f, 0.f};

  // ---- weights: bf16 fragments, register-resident ----
  bf16x8 bI0[3], bH0[3][4], bI1[3][4], bH1[3][4];
  #pragma unroll
  for (int gs = 0; gs < 3; ++gs)
    bI0[gs] = *(const bf16x8*)&wI0[(size_t)((w * 3 + gs) * 64 + l) * 8];
  #pragma unroll
  for (int gs = 0; gs < 3; ++gs)
    #pragma unroll
    for (int kc = 0; kc < 4; ++kc) {
      const size_t fi = (size_t)(((w * 3 + gs) * 4 + kc) * 64 + l) * 8;
      bH0[gs][kc] = *(const bf16x8*)&wH0[fi];
      bI1[gs][kc] = *(const bf16x8*)&wI1[fi];
      bH1[gs][kc] = *(const bf16x8*)&wH1[fi];
    }
  // Pin every fragment: value now originates from inline asm -> the
  // allocator cannot rematerialize it as a global reload in the loop.
  // At waves_per_eu(2,2) the budget is 256 VGPR/wave; 156 (weights) +
  // ~95 (state) fits WITHOUT losing 2-waves/SIMD occupancy (R9's mistake
  // was testing pins at 1 wave/SIMD with a 312-reg weight set).
  #pragma unroll
  for (int gs = 0; gs < 3; ++gs) {
    asm volatile("" : "+v"(bI0[gs]));
    #pragma unroll
    for (int kc = 0; kc < 4; ++kc) {
      asm volatile("" : "+v"(bH0[gs][kc]));
      asm volatile("" : "+v"(bI1[gs][kc]));
      asm volatile("" : "+v"(bH1[gs][kc]));
    }
  }

  const float L2E = 1.4426950408889634f;
  const float nBr0 = -L2E * (bih0[j] + bhh0[j]);
  const float nBz0 = -L2E * (bih0[128 + j] + bhh0[128 + j]);
  const float bin0 = bih0[256 + j], bhn0 = bhh0[256 + j];
  const float nBr1 = -L2E * (bih1[j] + bhh1[j]);
  const float nBz1 = -L2E * (bih1[128 + j] + bhh1[128 + j]);
  const float bin1 = bih1[256 + j], bhn1 = bhh1[256 + j];

  for (int i = tid; i < 16 * HH; i += 512) {
    s0a[i] = (__bf16)0.f; s0b[i] = (__bf16)0.f;
    s1a[i] = (__bf16)0.f; s1b[i] = (__bf16)0.f;
  }

  // ---- swizzled read offsets (elements): row lm, 16B block (kc*4+lq)^(lm&7)
  const int sw = lm & 7;
  int eo[4];
  #pragma unroll
  for (int kc = 0; kc < 4; ++kc)
    eo[kc] = lm * HH + ((((kc << 2) | lq) ^ sw) << 3);

  // ---- owned row / write offset / output indexing (fixed per thread)
  const int myrow = lq * 4 + Q0;
  const int woff  = myrow * HH + (((j >> 3) ^ (myrow & 7)) << 3) + (j & 7);
  const int seq   = gg * 16 + myrow;
  const int bidx  = seq / NNODE;
  const int node  = seq - bidx * NNODE;

  float h0p = 0.f, h1p = 0.f, hsum = 0.f;

  const __bf16* xrow = xb + (size_t)gg * TT * 512 + l * 8;
  bf16x8 a0 = *(const bf16x8*)xrow;          // t = 0 fragment
  __syncthreads();                           // init visible (full drain once)

  for (int t = 0; t < TT; ++t) {
    __bf16*       h0w = (t & 1) ? s0b : s0a;   // h0_t
    const __bf16* h0r = (t & 1) ? s0a : s0b;   // h0_{t-1}
    __bf16*       h1w = (t & 1) ? s1a : s1b;   // h1_{t-1}
    const __bf16* h1r = (t & 1) ? s1b : s1a;   // h1_{t-2}

    // prefetch next-step x fragment FIRST: rides across the step barrier.
    bf16x8 a0n = *(const bf16x8*)(xrow + (size_t)((t + 1) & (TT - 1)) * 512);

    bf16x8 ah0[4], ah1[4];
    #pragma unroll
    for (int kc = 0; kc < 4; ++kc) ah0[kc] = *(const bf16x8*)&h0r[eo[kc]];
    #pragma unroll
    for (int kc = 0; kc < 4; ++kc) ah1[kc] = *(const bf16x8*)&h1r[eo[kc]];

    // ---- L0 x-part first: no LDS dependence, issues before lgkm wait
    f32x4 Cr = mfma16(a0, bI0[0], z4);
    f32x4 Cz = mfma16(a0, bI0[1], z4);
    f32x4 Cn = mfma16(a0, bI0[2], z4);

    // ---- L1 MFMAs (step t-1): gi from h0_{t-1} (=ah0), rec from ah1
    f32x4 Dr = z4, Dz = z4, Dn = z4, Dm = z4;
    if (t > 0) {
      #pragma unroll
      for (int kc = 0; kc < 4; ++kc) {
        Dr = mfma16(ah0[kc], bI1[0][kc], Dr);
        Dz = mfma16(ah0[kc], bI1[1][kc], Dz);
        Dn = mfma16(ah0[kc], bI1[2][kc], Dn);
      }
      #pragma unroll
      for (int kc = 0; kc < 4; ++kc) {
        Dr = mfma16(ah1[kc], bH1[0][kc], Dr);
        Dz = mfma16(ah1[kc], bH1[1][kc], Dz);
        Dm = mfma16(ah1[kc], bH1[2][kc], Dm);
      }
    }

    // ---- L0 h-part
    f32x4 Cm = z4;
    #pragma unroll
    for (int kc = 0; kc < 4; ++kc) {
      Cr = mfma16(ah0[kc], bH0[0][kc], Cr);
      Cz = mfma16(ah0[kc], bH0[1][kc], Cz);
      Cm = mfma16(ah0[kc], bH0[2][kc], Cm);
    }

    // ---- L1 gates first (Dr ready earlier; overlaps L0 h-MFMAs in flight)
    if (t > 0) {
      const float h = gate_step(Dr[Q0], Dz[Q0], Dn[Q0], Dm[Q0],
                                nBr1, nBz1, bin1, bhn1, h1p);
      h1p = h;
      hsum += h;
      h1w[woff] = (__bf16)h;
      const int s = t - 1;
      if ((s & 255) == 255) {
        const int win = s >> 8;
        xg[((size_t)(bidx * NDYN + win) * NNODE + node) * HH + j] =
            hsum * (1.f / 256.f);
        hsum = 0.f;
      }
    }
    // ---- L0 gate
    {
      const float h = gate_step(Cr[Q0], Cz[Q0], Cn[Q0], Cm[Q0],
                                nBr0, nBz0, bin0, bhn0, h0p);
      h0p = h;
      h0w[woff] = (__bf16)h;
    }
    a0 = a0n;
    STEP_BARRIER();
  }

  // ---- epilogue: L1 step 2047 (h0_2047 in s0b, h1_2046 in s1a)
  {
    const __bf16* h0r = s0b;
    const __bf16* h1r = s1a;
    bf16x8 ah0[4], ah1[4];
    #pragma unroll
    for (int kc = 0; kc < 4; ++kc) ah0[kc] = *(const bf16x8*)&h0r[eo[kc]];
    #pragma unroll
    for (int kc = 0; kc < 4; ++kc) ah1[kc] = *(const bf16x8*)&h1r[eo[kc]];
    f32x4 Dr = z4, Dz = z4, Dn = z4, Dm = z4;
    #pragma unroll
    for (int kc = 0; kc < 4; ++kc) {
      Dr = mfma16(ah0[kc], bI1[0][kc], Dr);
      Dz = mfma16(ah0[kc], bI1[1][kc], Dz);
      Dn = mfma16(ah0[kc], bI1[2][kc], Dn);
    }
    #pragma unroll
    for (int kc = 0; kc < 4; ++kc) {
      Dr = mfma16(ah1[kc], bH1[0][kc], Dr);
      Dz = mfma16(ah1[kc], bH1[1][kc], Dz);
      Dm = mfma16(ah1[kc], bH1[2][kc], Dm);
    }
    const float h = gate_step(Dr[Q0], Dz[Q0], Dn[Q0], Dm[Q0],
                              nBr1, nBz1, bin1, bhn1, h1p);
    hsum += h;
    xg[((size_t)(bidx * NDYN + 7) * NNODE + node) * HH + j] =
        hsum * (1.f / 256.f);
  }
}

__global__ __launch_bounds__(512) __attribute__((amdgpu_waves_per_eu(2, 2)))
void gru2_kernel(
    const __bf16* __restrict__ xb,
    const __bf16* __restrict__ wI0, const __bf16* __restrict__ wH0,
    const __bf16* __restrict__ wI1, const __bf16* __restrict__ wH1,
    const float* __restrict__ bih0, const float* __restrict__ bhh0,
    const float* __restrict__ bih1, const float* __restrict__ bhh1,
    float* __restrict__ xg)
{
  __shared__ __align__(16) __bf16 sH0[2][16 * HH];
  __shared__ __align__(16) __bf16 sH1[2][16 * HH];
  const int gg = blockIdx.x >> 2;
  switch (blockIdx.x & 3) {
    case 0: gru_body<0>(xb, wI0, wH0, wI1, wH1, bih0, bhh0, bih1, bhh1, xg,
                        sH0[0], sH0[1], sH1[0], sH1[1], gg); break;
    case 1: gru_body<1>(xb, wI0, wH0, wI1, wH1, bih0, bhh0, bih1, bhh1, xg,
                        sH0[0], sH0[1], sH1[0], sH1[1], gg); break;
    case 2: gru_body<2>(xb, wI0, wH0, wI1, wH1, bih0, bhh0, bih1, bhh1, xg,
                        sH0[0], sH0[1], sH1[0], sH1[1], gg); break;
    default: gru_body<3>(xb, wI0, wH0, wI1, wH1, bih0, bhh0, bih1, bhh1, xg,
                         sH0[0], sH0[1], sH1[0], sH1[1], gg); break;
  }
}

// ---------------------------------------------------------------------------
// Per-graph stage (unchanged — verified, negligible time).
// ---------------------------------------------------------------------------
static __device__ __forceinline__ float blockReduce256(float v, float* sRed)
{
  const int tid = threadIdx.x;
  __syncthreads();
  sRed[tid] = v;
  __syncthreads();
  #pragma unroll
  for (int st = 128; st >= 1; st >>= 1) {
    if (tid < st) sRed[tid] += sRed[tid + st];
    __syncthreads();
  }
  return sRed[0];
}

__global__ __launch_bounds__(256) void graph_kernel(
    const float* __restrict__ xg,
    const float* __restrict__ Wq, const float* __restrict__ Wk,
    const float* __restrict__ Wl, const float* __restrict__ Wr,
    const float* __restrict__ bs, const float* __restrict__ Wc,
    float* __restrict__ out)
{
  const int tid = threadIdx.x;
  const int bp = blockIdx.x;

  __shared__ float sX[NNODE * HH];
  __shared__ float sQ[NNODE * HH];
  __shared__ float sK[NNODE * HH];
  __shared__ float sG[NNODE * NNODE];
  __shared__ float sA[NNODE * NNODE];
  __shared__ float sS[NNODE * NNODE];
  __shared__ float sNorm[NNODE];
  __shared__ float sDis[NNODE];
  __shared__ float sDeg[NNODE];
  __shared__ float sThr;
  __shared__ float sRed[256];

  for (int idx = tid; idx < NNODE * HH; idx += 256)
    sX[idx] = xg[(size_t)bp * NNODE * HH + idx];
  __syncthreads();

  if (tid < NNODE) {
    float acc = 0.f;
    const float* xv = &sX[tid * HH];
    #pragma unroll 4
    for (int d = 0; d < HH; ++d) acc += xv[d] * xv[d];
    sNorm[tid] = 1.f / sqrtf(acc);
  }
  for (int e = tid; e < NNODE * NNODE; e += 256) {
    const int n = e / NNODE, m = e % NNODE;
    float acc = 0.f;
    const float* a = &sX[n * HH];
    const float* b = &sX[m * HH];
    #pragma unroll 4
    for (int d = 0; d < HH; ++d) acc += a[d] * b[d];
    sG[e] = acc;
  }
  for (int e = tid; e < NNODE * NNODE; e += 256) sA[e] = 0.f;
  __syncthreads();

  if (tid < NNODE) {
    const int r = tid;
    const float nr = sNorm[r];
    float v0 = -1e30f, v1 = -1e30f, v2 = -1e30f;
    int i0 = 0, i1 = 0, i2 = 0;
    for (int m = 0; m < NNODE; ++m) {
      const float v = sG[r * NNODE + m] * nr * sNorm[m];
      if (v > v0)      { v2 = v1; i2 = i1; v1 = v0; i1 = i0; v0 = v; i0 = m; }
      else if (v > v1) { v2 = v1; i2 = i1; v1 = v;  i1 = m; }
      else if (v > v2) { v2 = v;  i2 = m; }
    }
    sA[r * NNODE + i0] = fmaxf(v0, 0.f);
    sA[r * NNODE + i1] = fmaxf(v1, 0.f);
    sA[r * NNODE + i2] = fmaxf(v2, 0.f);
  }
  __syncthreads();

  {
    float t0 = 0.f, t1 = 0.f;
    if (tid < 361) {
      const int n = tid / NNODE, m = tid % NNODE;
      t0 = (n == m) ? 1.f : 0.5f * (sA[n * NNODE + m] + sA[m * NNODE + n]);
    }
    if (tid + 256 < 361) {
      const int e = tid + 256;
      const int n = e / NNODE, m = e % NNODE;
      t1 = (n == m) ? 1.f : 0.5f * (sA[n * NNODE + m] + sA[m * NNODE + n]);
    }
    __syncthreads();
    if (tid < 361) sA[tid] = t0;
    if (tid + 256 < 361) sA[tid + 256] = t1;
  }

  for (int o = tid; o < NNODE * HH; o += 256) {
    const int n = o >> 7, hh = o & 127;
    float aq = 0.f, ak = 0.f;
    const float* xv = &sX[n * HH];
    const float* wq = &Wq[hh * HH];
    const float* wk = &Wk[hh * HH];
    #pragma unroll 4
    for (int d = 0; d < HH; ++d) { const float xx = xv[d]; aq += xx * wq[d]; ak += xx * wk[d]; }
    sQ[o] = aq; sK[o] = ak;
  }
  __syncthreads();

  for (int e = tid; e < NNODE * NNODE; e += 256) {
    const int n = e / NNODE, m = e % NNODE;
    float acc = 0.f;
    const float* a = &sQ[n * HH];
    const float* b = &sK[m * HH];
    #pragma unroll 4
    for (int d = 0; d < HH; ++d) acc += a[d] * b[d];
    sS[e] = acc * 0.08838834764831845f;
  }
  __syncthreads();
  if (tid < NNODE) {
    const int r = tid;
    float mx = -1e30f;
    for (int m = 0; m < NNODE; ++m) mx = fmaxf(mx, sS[r * NNODE + m]);
    float sum = 0.f;
    for (int m = 0; m < NNODE; ++m) sum += expf(sS[r * NNODE + m] - mx);
    const float inv = 1.f / sum;
    for (int m = 0; m < NNODE; ++m)
      sS[r * NNODE + m] = expf(sS[r * NNODE + m] - mx) * inv;
  }
  __syncthreads();

  for (int e = tid; e < NNODE * NNODE; e += 256) {
    const int n = e / NNODE, m = e % NNODE;
    sA[e] = 0.1f * sA[e] + 0.45f * (sS[n * NNODE + m] + sS[m * NNODE + n]);
  }
  __syncthreads();

  for (int e = tid; e < NNODE * NNODE; e += 256) {
    const float v = sA[e];
    int cg = 0, ce = 0;
    for (int f = 0; f < NNODE * NNODE; ++f) {
      const float u = sA[f];
      cg += (u > v);
      ce += (u == v);
    }
    if (cg <= 180 && cg + ce > 180) sThr = v;
  }
  __syncthreads();
  {
    const float thr = sThr;
    for (int e = tid; e < NNODE * NNODE; e += 256)
      sA[e] = (sA[e] > thr) ? sA[e] : 0.f;
  }
  __syncthreads();

  if (tid < NNODE) {
    const int r = tid;
    float dsum = 0.f;
    int cnt = 0;
    for (int m = 0; m < NNODE; ++m) {
      const float v = sA[r * NNODE + m];
      dsum += v;
      if (m != r && v > 0.f) ++cnt;
    }
    sDis[r] = (dsum > 0.f) ? 1.f / sqrtf(dsum) : 0.f;
    sDeg[r] = (float)(cnt < 1 ? 1 : cnt);
  }
  __syncthreads();

  float regp = 0.f;
  for (int e = tid; e < NNODE * NNODE; e += 256) {
    const int n = e / NNODE, m = e % NNODE;
    const float Lnm = ((n == m) ? 1.f : 0.f) - sDis[n] * sDis[m] * sA[e];
    regp += Lnm * sG[e];
  }
  {
    const float tr = blockReduce256(regp, sRed);
    if (tid == 0)
      atomicAdd(out + 16, tr * (1.f / (16384.f * (float)NGRAPH)));
  }
  __syncthreads();

  for (int o = tid; o < NNODE * HH; o += 256) {
    const int n = o >> 7, d = o & 127;
    float acc = 0.f;
    for (int m = 0; m < NNODE; ++m)
      if (m != n && sA[n * NNODE + m] > 0.f) acc += sX[m * HH + d];
    sQ[o] = acc / sDeg[n];
  }
  __syncthreads();

  float lgp = 0.f;
  for (int o = tid; o < NNODE * HH; o += 256) {
    const int n = o >> 7, hh = o & 127;
    float acc = bs[hh];
    const float* av = &sQ[n * HH];
    const float* xv = &sX[n * HH];
    const float* wl = &Wl[hh * HH];
    const float* wr = &Wr[hh * HH];
    #pragma unroll 4
    for (int d = 0; d < HH; ++d) acc += av[d] * wl[d] + xv[d] * wr[d];
    lgp += fmaxf(acc, 0.f) * Wc[hh];
  }
  {
    const float tot = blockReduce256(lgp, sRed);
    if (tid == 0)
      atomicAdd(out + (bp >> 3), tot * 0.125f);
  }
}

__global__ void init_out_kernel(float* __restrict__ out, const float* __restrict__ bc)
{
  const int i = threadIdx.x;
  if (i < 16) out[i] = bc[0];
  else if (i == 16) out[16] = 0.f;
}

// ---------------------------------------------------------------------------
extern "C" void kernel_launch(void* const* d_in, const int* in_sizes, int n_in,
                              void* d_out, int out_size, void* d_ws, size_t ws_size,
                              hipStream_t stream)
{
  const float* x    = (const float*)d_in[0];
  const float* Wih0 = (const float*)d_in[1];
  const float* Whh0 = (const float*)d_in[2];
  const float* bih0 = (const float*)d_in[3];
  const float* bhh0 = (const float*)d_in[4];
  const float* Wih1 = (const float*)d_in[5];
  const float* Whh1 = (const float*)d_in[6];
  const float* bih1 = (const float*)d_in[7];
  const float* bhh1 = (const float*)d_in[8];
  const float* Wq   = (const float*)d_in[9];
  const float* Wk   = (const float*)d_in[10];
  const float* Wl   = (const float*)d_in[11];
  const float* Wr   = (const float*)d_in[12];
  const float* bsg  = (const float*)d_in[13];
  const float* Wc   = (const float*)d_in[14];
  const float* bc   = (const float*)d_in[15];
  float* out = (float*)d_out;

  // workspace layout
  const size_t XB  = (size_t)NNODE * TT * 512 * sizeof(__bf16);  // 39.8 MB
  const size_t WI0 = (size_t)8 * 3 * 64 * 8 * sizeof(__bf16);    // 24 KB
  const size_t WH  = (size_t)8 * 3 * 4 * 64 * 8 * sizeof(__bf16);// 96 KB
  char* p = (char*)d_ws;
  __bf16* xb  = (__bf16*)p;            p += XB;
  __bf16* wI0 = (__bf16*)p;            p += WI0;
  __bf16* wH0 = (__bf16*)p;            p += WH;
  __bf16* wI1 = (__bf16*)p;            p += WH;
  __bf16* wH1 = (__bf16*)p;            p += WH;
  float*  xg  = (float*)p;

  init_out_kernel<<<1, 64, 0, stream>>>(out, bc);
  wprep_kernel<<<6, 256, 0, stream>>>(Wih0, wI0, 32, 1);
  wprep_kernel<<<24, 256, 0, stream>>>(Whh0, wH0, 128, 4);
  wprep_kernel<<<24, 256, 0, stream>>>(Whh1, wH1, 128, 4);
  wprep_kernel<<<24, 256, 0, stream>>>(Wih1, wI1, 128, 4);
  xprep_kernel<<<(NNODE * TT * 64 + 255) / 256, 256, 0, stream>>>(x, xb);
  gru2_kernel<<<NBLK, 512, 0, stream>>>(
      xb, wI0, wH0, wI1, wH1, bih0, bhh0, bih1, bhh1, xg);
  graph_kernel<<<NGRAPH, 256, 0, stream>>>(xg, Wq, Wk, Wl, Wr, bsg, Wc, out);
}

// Round 7
// 2017.882 us; speedup vs baseline: 1.3028x; 1.0033x over previous
//
#include <hip/hip_runtime.h>
#include <hip/hip_bf16.h>

// ---------------------------------------------------------------------------
// GraphS4mer forward, R11: COMPACT 4-row h-tiles + quad-broadcast LDS reads.
//   R10 post-mortem: additive step budget at 2074 cyc = MFMA 378 + VALU ~360
//   + LDS pipe 768 service + 256 conflicts + ~300 slop. LDS is the dominant
//   removable term. With q-split, only 4 of 16 h-rows are nonzero; the
//   A-fragment address depends on lm only via r=lm>>2, so storing h compact
//   (4 rows x stride 160) makes all 4 lanes of each lm-quad read the SAME
//   address -> LDS broadcast (free). 8 reads/wave touch 16 unique 16B blocks
//   (256B) instead of 64 (1KB): ~4x less LDS pipe time. Duplicate data feeds
//   only UNUSED C rows (used row R=4lq+Q0 reads lane lm=R -> compact row lq
//   -> h[R] exact) -> bitwise-identical output. blk^row XOR + stride 160
//   keeps residual aliasing 2-way (free). Everything else = R10.
// ---------------------------------------------------------------------------

#define NSEQ   304
#define TT     2048
#define HH     128
#define NNODE  19
#define NDYN   8
#define NGRAPH 128
#define NBLK   76             // 4 blocks per 16-seq group, q-split
#define CPITCH 160            // compact h row stride (elements): 320B = 20*16B

typedef __bf16 bf16x8 __attribute__((ext_vector_type(8)));
typedef float  f32x4  __attribute__((ext_vector_type(4)));

static __device__ __forceinline__ f32x4 mfma16(bf16x8 a, bf16x8 b, f32x4 c) {
  return __builtin_amdgcn_mfma_f32_16x16x32_bf16(a, b, c, 0, 0, 0);
}

// GRU gate update: r=sig(cr+Br), z=sig(cz+Bz), n=tanh(cn+bin + r*(cm+bhn)),
// h = n + z*(hp-n).  nBr/nBz are -log2(e)*(bih+bhh) prefolded.
static __device__ __forceinline__ float gate_step(
    float cr, float cz, float cn, float cm,
    float nBr, float nBz, float bin, float bhn, float hp)
{
  const float er = __builtin_amdgcn_exp2f(__builtin_fmaf(cr, -1.4426950408889634f, nBr));
  const float ez = __builtin_amdgcn_exp2f(__builtin_fmaf(cz, -1.4426950408889634f, nBz));
  const float r  = __builtin_amdgcn_rcpf(1.f + er);
  const float z  = __builtin_amdgcn_rcpf(1.f + ez);
  const float gn = __builtin_fmaf(r, cm + bhn, cn + bin);
  const float en = __builtin_amdgcn_exp2f(gn * 2.8853900817779268f);   // e^(2gn)
  const float nn = __builtin_fmaf(__builtin_amdgcn_rcpf(1.f + en), -2.f, 1.f);
  return __builtin_fmaf(z, hp - nn, nn);
}

// ---------------------------------------------------------------------------
// Prep: weights -> bf16 fragment order. dst[((w*3+gs)*nk+kc)*64+l][8] =
//   src[(128*gs+16*w+(l&15))*K + kc*32 + (l>>4)*8 + u]
// ---------------------------------------------------------------------------
__global__ void wprep_kernel(const float* __restrict__ src, __bf16* __restrict__ dst,
                             int K, int nk)
{
  const int i = blockIdx.x * 256 + threadIdx.x;
  const int total = 8 * 3 * nk * 64;
  if (i >= total) return;
  const int l = i & 63;
  int rest = i >> 6;
  const int kc = rest % nk; rest /= nk;
  const int gs = rest % 3;
  const int w  = rest / 3;
  const int row = 128 * gs + 16 * w + (l & 15);
  const float* s = src + (size_t)row * K + kc * 32 + (l >> 4) * 8;
  bf16x8 v;
  #pragma unroll
  for (int u = 0; u < 8; ++u) v[u] = (__bf16)s[u];
  *(bf16x8*)&dst[(size_t)i * 8] = v;
}

// x -> bf16 A-fragment layout: xb[((g*TT+t)*64+l)*8+u] =
//   x[(g*16+(l&15))*TT*32 + t*32 + (l>>4)*8 + u]
__global__ void xprep_kernel(const float* __restrict__ x, __bf16* __restrict__ xb)
{
  const int i = blockIdx.x * 256 + threadIdx.x;
  if (i >= NNODE * TT * 64) return;
  const int l = i & 63;
  const int t = (i >> 6) & (TT - 1);
  const int g = i >> 17;                       // 64*2048 = 2^17
  const float* s = x + ((size_t)(g * 16 + (l & 15)) * TT + t) * 32 + (l >> 4) * 8;
  bf16x8 v;
  #pragma unroll
  for (int u = 0; u < 8; ++u) v[u] = (__bf16)s[u];
  *(bf16x8*)&xb[(size_t)i * 8] = v;
}

// ---------------------------------------------------------------------------
// LDS-only step barrier (R8-verified): ds ops retired before s_barrier;
// vmcnt NOT drained -> x prefetch rides across steps.
// ---------------------------------------------------------------------------
#define STEP_BARRIER() do {                                          \
    asm volatile("s_waitcnt lgkmcnt(0)" ::: "memory");               \
    __builtin_amdgcn_s_barrier();                                    \
    __builtin_amdgcn_sched_barrier(0);                               \
  } while (0)

// ---------------------------------------------------------------------------
// Templated GRU body: Q0 = owned acc-row slot (block-uniform).
// Compact h-LDS: 4 rows (compact row rho holds real row 4*rho+Q0), stride
// CPITCH=160 elem; 16B block b of row rho stored at b' = b ^ rho.
// Reads: lane l uses r=lm>>2 -> all 4 lanes of an lm-quad share one address
// (broadcast). Used C row R=4lq+Q0 draws A from lane lm=R, which reads
// compact row lq = h[R] exactly; other lanes' duplicates feed unused C rows.
// ---------------------------------------------------------------------------
template<int Q0>
static __device__ __forceinline__ void gru_body(
    const __bf16* __restrict__ xb,
    const __bf16* __restrict__ wI0, const __bf16* __restrict__ wH0,
    const __bf16* __restrict__ wI1, const __bf16* __restrict__ wH1,
    const float* __restrict__ bih0, const float* __restrict__ bhh0,
    const float* __restrict__ bih1, const float* __restrict__ bhh1,
    float* __restrict__ xg,
    __bf16* s0a, __bf16* s0b, __bf16* s1a, __bf16* s1b, int gg)
{
  const int tid = threadIdx.x;
  const int w   = tid >> 6;
  const int l   = tid & 63;
  const int lm  = l & 15;
  const int lq  = l >> 4;
  const int j   = 16 * w + lm;
  const f32x4 z4 = {0.f, 0.f, 0.f, 0.f};

  // ---- weights: bf16 fragments, register-resident ----
  bf16x8 bI0[3], bH0[3][4], bI1[3][4], bH1[3][4];
  #pragma unroll
  for (int gs = 0; gs < 3; ++gs)
    bI0[gs] = *(const bf16x8*)&wI0[(size_t)((w * 3 + gs) * 64 + l) * 8];
  #pragma unroll
  for (int gs = 0; gs < 3; ++gs)
    #pragma unroll
    for (int kc = 0; kc < 4; ++kc) {
      const size_t fi = (size_t)(((w * 3 + gs) * 4 + kc) * 64 + l) * 8;
      bH0[gs][kc] = *(const bf16x8*)&wH0[fi];
      bI1[gs][kc] = *(const bf16x8*)&wI1[fi];
      bH1[gs][kc] = *(const bf16x8*)&wH1[fi];
    }
  #pragma unroll
  for (int gs = 0; gs < 3; ++gs) {
    asm volatile("" : "+v"(bI0[gs]));
    #pragma unroll
    for (int kc = 0; kc < 4; ++kc) {
      asm volatile("" : "+v"(bH0[gs][kc]));
      asm volatile("" : "+v"(bI1[gs][kc]));
      asm volatile("" : "+v"(bH1[gs][kc]));
    }
  }

  const float L2E = 1.4426950408889634f;
  const float nBr0 = -L2E * (bih0[j] + bhh0[j]);
  const float nBz0 = -L2E * (bih0[128 + j] + bhh0[128 + j]);
  const float bin0 = bih0[256 + j], bhn0 = bhh0[256 + j];
  const float nBr1 = -L2E * (bih1[j] + bhh1[j]);
  const float nBz1 = -L2E * (bih1[128 + j] + bhh1[128 + j]);
  const float bin1 = bih1[256 + j], bhn1 = bhh1[256 + j];

  for (int i = tid; i < 4 * CPITCH; i += 512) {
    s0a[i] = (__bf16)0.f; s0b[i] = (__bf16)0.f;
    s1a[i] = (__bf16)0.f; s1b[i] = (__bf16)0.f;
  }

  // ---- compact read offsets: quad-shared address (r = lm>>2)
  const int rr = lm >> 2;
  int eo[4];
  #pragma unroll
  for (int kc = 0; kc < 4; ++kc)
    eo[kc] = rr * CPITCH + ((((kc << 2) | lq) ^ rr) << 3);

  // ---- owned row / compact write offset / output indexing
  const int myrow = lq * 4 + Q0;               // real h row this thread owns
  const int woff  = lq * CPITCH + (((j >> 3) ^ lq) << 3) + (j & 7);
  const int seq   = gg * 16 + myrow;
  const int bidx  = seq / NNODE;
  const int node  = seq - bidx * NNODE;

  float h0p = 0.f, h1p = 0.f, hsum = 0.f;

  const __bf16* xrow = xb + (size_t)gg * TT * 512 + l * 8;
  bf16x8 a0 = *(const bf16x8*)xrow;          // t = 0 fragment
  __syncthreads();                           // init visible (full drain once)

  for (int t = 0; t < TT; ++t) {
    __bf16*       h0w = (t & 1) ? s0b : s0a;   // h0_t
    const __bf16* h0r = (t & 1) ? s0a : s0b;   // h0_{t-1}
    __bf16*       h1w = (t & 1) ? s1a : s1b;   // h1_{t-1}
    const __bf16* h1r = (t & 1) ? s1b : s1a;   // h1_{t-2}

    // prefetch next-step x fragment FIRST: rides across the step barrier.
    bf16x8 a0n = *(const bf16x8*)(xrow + (size_t)((t + 1) & (TT - 1)) * 512);

    bf16x8 ah0[4], ah1[4];
    #pragma unroll
    for (int kc = 0; kc < 4; ++kc) ah0[kc] = *(const bf16x8*)&h0r[eo[kc]];
    #pragma unroll
    for (int kc = 0; kc < 4; ++kc) ah1[kc] = *(const bf16x8*)&h1r[eo[kc]];

    // ---- L0 x-part first: no LDS dependence, issues before lgkm wait
    f32x4 Cr = mfma16(a0, bI0[0], z4);
    f32x4 Cz = mfma16(a0, bI0[1], z4);
    f32x4 Cn = mfma16(a0, bI0[2], z4);

    // ---- L1 MFMAs (step t-1): gi from h0_{t-1} (=ah0), rec from ah1
    f32x4 Dr = z4, Dz = z4, Dn = z4, Dm = z4;
    if (t > 0) {
      #pragma unroll
      for (int kc = 0; kc < 4; ++kc) {
        Dr = mfma16(ah0[kc], bI1[0][kc], Dr);
        Dz = mfma16(ah0[kc], bI1[1][kc], Dz);
        Dn = mfma16(ah0[kc], bI1[2][kc], Dn);
      }
      #pragma unroll
      for (int kc = 0; kc < 4; ++kc) {
        Dr = mfma16(ah1[kc], bH1[0][kc], Dr);
        Dz = mfma16(ah1[kc], bH1[1][kc], Dz);
        Dm = mfma16(ah1[kc], bH1[2][kc], Dm);
      }
    }

    // ---- L0 h-part
    f32x4 Cm = z4;
    #pragma unroll
    for (int kc = 0; kc < 4; ++kc) {
      Cr = mfma16(ah0[kc], bH0[0][kc], Cr);
      Cz = mfma16(ah0[kc], bH0[1][kc], Cz);
      Cm = mfma16(ah0[kc], bH0[2][kc], Cm);
    }

    // ---- L1 gates first (Dr ready earlier; overlaps L0 h-MFMAs in flight)
    if (t > 0) {
      const float h = gate_step(Dr[Q0], Dz[Q0], Dn[Q0], Dm[Q0],
                                nBr1, nBz1, bin1, bhn1, h1p);
      h1p = h;
      hsum += h;
      h1w[woff] = (__bf16)h;
      const int s = t - 1;
      if ((s & 255) == 255) {
        const int win = s >> 8;
        xg[((size_t)(bidx * NDYN + win) * NNODE + node) * HH + j] =
            hsum * (1.f / 256.f);
        hsum = 0.f;
      }
    }
    // ---- L0 gate
    {
      const float h = gate_step(Cr[Q0], Cz[Q0], Cn[Q0], Cm[Q0],
                                nBr0, nBz0, bin0, bhn0, h0p);
      h0p = h;
      h0w[woff] = (__bf16)h;
    }
    a0 = a0n;
    STEP_BARRIER();
  }

  // ---- epilogue: L1 step 2047 (h0_2047 in s0b, h1_2046 in s1a)
  {
    const __bf16* h0r = s0b;
    const __bf16* h1r = s1a;
    bf16x8 ah0[4], ah1[4];
    #pragma unroll
    for (int kc = 0; kc < 4; ++kc) ah0[kc] = *(const bf16x8*)&h0r[eo[kc]];
    #pragma unroll
    for (int kc = 0; kc < 4; ++kc) ah1[kc] = *(const bf16x8*)&h1r[eo[kc]];
    f32x4 Dr = z4, Dz = z4, Dn = z4, Dm = z4;
    #pragma unroll
    for (int kc = 0; kc < 4; ++kc) {
      Dr = mfma16(ah0[kc], bI1[0][kc], Dr);
      Dz = mfma16(ah0[kc], bI1[1][kc], Dz);
      Dn = mfma16(ah0[kc], bI1[2][kc], Dn);
    }
    #pragma unroll
    for (int kc = 0; kc < 4; ++kc) {
      Dr = mfma16(ah1[kc], bH1[0][kc], Dr);
      Dz = mfma16(ah1[kc], bH1[1][kc], Dz);
      Dm = mfma16(ah1[kc], bH1[2][kc], Dm);
    }
    const float h = gate_step(Dr[Q0], Dz[Q0], Dn[Q0], Dm[Q0],
                              nBr1, nBz1, bin1, bhn1, h1p);
    hsum += h;
    xg[((size_t)(bidx * NDYN + 7) * NNODE + node) * HH + j] =
        hsum * (1.f / 256.f);
  }
}

__global__ __launch_bounds__(512) __attribute__((amdgpu_waves_per_eu(2, 2)))
void gru2_kernel(
    const __bf16* __restrict__ xb,
    const __bf16* __restrict__ wI0, const __bf16* __restrict__ wH0,
    const __bf16* __restrict__ wI1, const __bf16* __restrict__ wH1,
    const float* __restrict__ bih0, const float* __restrict__ bhh0,
    const float* __restrict__ bih1, const float* __restrict__ bhh1,
    float* __restrict__ xg)
{
  __shared__ __align__(16) __bf16 sH0[2][4 * CPITCH];
  __shared__ __align__(16) __bf16 sH1[2][4 * CPITCH];
  const int gg = blockIdx.x >> 2;
  switch (blockIdx.x & 3) {
    case 0: gru_body<0>(xb, wI0, wH0, wI1, wH1, bih0, bhh0, bih1, bhh1, xg,
                        sH0[0], sH0[1], sH1[0], sH1[1], gg); break;
    case 1: gru_body<1>(xb, wI0, wH0, wI1, wH1, bih0, bhh0, bih1, bhh1, xg,
                        sH0[0], sH0[1], sH1[0], sH1[1], gg); break;
    case 2: gru_body<2>(xb, wI0, wH0, wI1, wH1, bih0, bhh0, bih1, bhh1, xg,
                        sH0[0], sH0[1], sH1[0], sH1[1], gg); break;
    default: gru_body<3>(xb, wI0, wH0, wI1, wH1, bih0, bhh0, bih1, bhh1, xg,
                         sH0[0], sH0[1], sH1[0], sH1[1], gg); break;
  }
}

// ---------------------------------------------------------------------------
// Per-graph stage (unchanged — verified, negligible time).
// ---------------------------------------------------------------------------
static __device__ __forceinline__ float blockReduce256(float v, float* sRed)
{
  const int tid = threadIdx.x;
  __syncthreads();
  sRed[tid] = v;
  __syncthreads();
  #pragma unroll
  for (int st = 128; st >= 1; st >>= 1) {
    if (tid < st) sRed[tid] += sRed[tid + st];
    __syncthreads();
  }
  return sRed[0];
}

__global__ __launch_bounds__(256) void graph_kernel(
    const float* __restrict__ xg,
    const float* __restrict__ Wq, const float* __restrict__ Wk,
    const float* __restrict__ Wl, const float* __restrict__ Wr,
    const float* __restrict__ bs, const float* __restrict__ Wc,
    float* __restrict__ out)
{
  const int tid = threadIdx.x;
  const int bp = blockIdx.x;

  __shared__ float sX[NNODE * HH];
  __shared__ float sQ[NNODE * HH];
  __shared__ float sK[NNODE * HH];
  __shared__ float sG[NNODE * NNODE];
  __shared__ float sA[NNODE * NNODE];
  __shared__ float sS[NNODE * NNODE];
  __shared__ float sNorm[NNODE];
  __shared__ float sDis[NNODE];
  __shared__ float sDeg[NNODE];
  __shared__ float sThr;
  __shared__ float sRed[256];

  for (int idx = tid; idx < NNODE * HH; idx += 256)
    sX[idx] = xg[(size_t)bp * NNODE * HH + idx];
  __syncthreads();

  if (tid < NNODE) {
    float acc = 0.f;
    const float* xv = &sX[tid * HH];
    #pragma unroll 4
    for (int d = 0; d < HH; ++d) acc += xv[d] * xv[d];
    sNorm[tid] = 1.f / sqrtf(acc);
  }
  for (int e = tid; e < NNODE * NNODE; e += 256) {
    const int n = e / NNODE, m = e % NNODE;
    float acc = 0.f;
    const float* a = &sX[n * HH];
    const float* b = &sX[m * HH];
    #pragma unroll 4
    for (int d = 0; d < HH; ++d) acc += a[d] * b[d];
    sG[e] = acc;
  }
  for (int e = tid; e < NNODE * NNODE; e += 256) sA[e] = 0.f;
  __syncthreads();

  if (tid < NNODE) {
    const int r = tid;
    const float nr = sNorm[r];
    float v0 = -1e30f, v1 = -1e30f, v2 = -1e30f;
    int i0 = 0, i1 = 0, i2 = 0;
    for (int m = 0; m < NNODE; ++m) {
      const float v = sG[r * NNODE + m] * nr * sNorm[m];
      if (v > v0)      { v2 = v1; i2 = i1; v1 = v0; i1 = i0; v0 = v; i0 = m; }
      else if (v > v1) { v2 = v1; i2 = i1; v1 = v;  i1 = m; }
      else if (v > v2) { v2 = v;  i2 = m; }
    }
    sA[r * NNODE + i0] = fmaxf(v0, 0.f);
    sA[r * NNODE + i1] = fmaxf(v1, 0.f);
    sA[r * NNODE + i2] = fmaxf(v2, 0.f);
  }
  __syncthreads();

  {
    float t0 = 0.f, t1 = 0.f;
    if (tid < 361) {
      const int n = tid / NNODE, m = tid % NNODE;
      t0 = (n == m) ? 1.f : 0.5f * (sA[n * NNODE + m] + sA[m * NNODE + n]);
    }
    if (tid + 256 < 361) {
      const int e = tid + 256;
      const int n = e / NNODE, m = e % NNODE;
      t1 = (n == m) ? 1.f : 0.5f * (sA[n * NNODE + m] + sA[m * NNODE + n]);
    }
    __syncthreads();
    if (tid < 361) sA[tid] = t0;
    if (tid + 256 < 361) sA[tid + 256] = t1;
  }

  for (int o = tid; o < NNODE * HH; o += 256) {
    const int n = o >> 7, hh = o & 127;
    float aq = 0.f, ak = 0.f;
    const float* xv = &sX[n * HH];
    const float* wq = &Wq[hh * HH];
    const float* wk = &Wk[hh * HH];
    #pragma unroll 4
    for (int d = 0; d < HH; ++d) { const float xx = xv[d]; aq += xx * wq[d]; ak += xx * wk[d]; }
    sQ[o] = aq; sK[o] = ak;
  }
  __syncthreads();

  for (int e = tid; e < NNODE * NNODE; e += 256) {
    const int n = e / NNODE, m = e % NNODE;
    float acc = 0.f;
    const float* a = &sQ[n * HH];
    const float* b = &sK[m * HH];
    #pragma unroll 4
    for (int d = 0; d < HH; ++d) acc += a[d] * b[d];
    sS[e] = acc * 0.08838834764831845f;
  }
  __syncthreads();
  if (tid < NNODE) {
    const int r = tid;
    float mx = -1e30f;
    for (int m = 0; m < NNODE; ++m) mx = fmaxf(mx, sS[r * NNODE + m]);
    float sum = 0.f;
    for (int m = 0; m < NNODE; ++m) sum += expf(sS[r * NNODE + m] - mx);
    const float inv = 1.f / sum;
    for (int m = 0; m < NNODE; ++m)
      sS[r * NNODE + m] = expf(sS[r * NNODE + m] - mx) * inv;
  }
  __syncthreads();

  for (int e = tid; e < NNODE * NNODE; e += 256) {
    const int n = e / NNODE, m = e % NNODE;
    sA[e] = 0.1f * sA[e] + 0.45f * (sS[n * NNODE + m] + sS[m * NNODE + n]);
  }
  __syncthreads();

  for (int e = tid; e < NNODE * NNODE; e += 256) {
    const float v = sA[e];
    int cg = 0, ce = 0;
    for (int f = 0; f < NNODE * NNODE; ++f) {
      const float u = sA[f];
      cg += (u > v);
      ce += (u == v);
    }
    if (cg <= 180 && cg + ce > 180) sThr = v;
  }
  __syncthreads();
  {
    const float thr = sThr;
    for (int e = tid; e < NNODE * NNODE; e += 256)
      sA[e] = (sA[e] > thr) ? sA[e] : 0.f;
  }
  __syncthreads();

  if (tid < NNODE) {
    const int r = tid;
    float dsum = 0.f;
    int cnt = 0;
    for (int m = 0; m < NNODE; ++m) {
      const float v = sA[r * NNODE + m];
      dsum += v;
      if (m != r && v > 0.f) ++cnt;
    }
    sDis[r] = (dsum > 0.f) ? 1.f / sqrtf(dsum) : 0.f;
    sDeg[r] = (float)(cnt < 1 ? 1 : cnt);
  }
  __syncthreads();

  float regp = 0.f;
  for (int e = tid; e < NNODE * NNODE; e += 256) {
    const int n = e / NNODE, m = e % NNODE;
    const float Lnm = ((n == m) ? 1.f : 0.f) - sDis[n] * sDis[m] * sA[e];
    regp += Lnm * sG[e];
  }
  {
    const float tr = blockReduce256(regp, sRed);
    if (tid == 0)
      atomicAdd(out + 16, tr * (1.f / (16384.f * (float)NGRAPH)));
  }
  __syncthreads();

  for (int o = tid; o < NNODE * HH; o += 256) {
    const int n = o >> 7, d = o & 127;
    float acc = 0.f;
    for (int m = 0; m < NNODE; ++m)
      if (m != n && sA[n * NNODE + m] > 0.f) acc += sX[m * HH + d];
    sQ[o] = acc / sDeg[n];
  }
  __syncthreads();

  float lgp = 0.f;
  for (int o = tid; o < NNODE * HH; o += 256) {
    const int n = o >> 7, hh = o & 127;
    float acc = bs[hh];
    const float* av = &sQ[n * HH];
    const float* xv = &sX[n * HH];
    const float* wl = &Wl[hh * HH];
    const float* wr = &Wr[hh * HH];
    #pragma unroll 4
    for (int d = 0; d < HH; ++d) acc += av[d] * wl[d] + xv[d] * wr[d];
    lgp += fmaxf(acc, 0.f) * Wc[hh];
  }
  {
    const float tot = blockReduce256(lgp, sRed);
    if (tid == 0)
      atomicAdd(out + (bp >> 3), tot * 0.125f);
  }
}

__global__ void init_out_kernel(float* __restrict__ out, const float* __restrict__ bc)
{
  const int i = threadIdx.x;
  if (i < 16) out[i] = bc[0];
  else if (i == 16) out[16] = 0.f;
}

// ---------------------------------------------------------------------------
extern "C" void kernel_launch(void* const* d_in, const int* in_sizes, int n_in,
                              void* d_out, int out_size, void* d_ws, size_t ws_size,
                              hipStream_t stream)
{
  const float* x    = (const float*)d_in[0];
  const float* Wih0 = (const float*)d_in[1];
  const float* Whh0 = (const float*)d_in[2];
  const float* bih0 = (const float*)d_in[3];
  const float* bhh0 = (const float*)d_in[4];
  const float* Wih1 = (const float*)d_in[5];
  const float* Whh1 = (const float*)d_in[6];
  const float* bih1 = (const float*)d_in[7];
  const float* bhh1 = (const float*)d_in[8];
  const float* Wq   = (const float*)d_in[9];
  const float* Wk   = (const float*)d_in[10];
  const float* Wl   = (const float*)d_in[11];
  const float* Wr   = (const float*)d_in[12];
  const float* bsg  = (const float*)d_in[13];
  const float* Wc   = (const float*)d_in[14];
  const float* bc   = (const float*)d_in[15];
  float* out = (float*)d_out;

  // workspace layout
  const size_t XB  = (size_t)NNODE * TT * 512 * sizeof(__bf16);  // 39.8 MB
  const size_t WI0 = (size_t)8 * 3 * 64 * 8 * sizeof(__bf16);    // 24 KB
  const size_t WH  = (size_t)8 * 3 * 4 * 64 * 8 * sizeof(__bf16);// 96 KB
  char* p = (char*)d_ws;
  __bf16* xb  = (__bf16*)p;            p += XB;
  __bf16* wI0 = (__bf16*)p;            p += WI0;
  __bf16* wH0 = (__bf16*)p;            p += WH;
  __bf16* wI1 = (__bf16*)p;            p += WH;
  __bf16* wH1 = (__bf16*)p;            p += WH;
  float*  xg  = (float*)p;

  init_out_kernel<<<1, 64, 0, stream>>>(out, bc);
  wprep_kernel<<<6, 256, 0, stream>>>(Wih0, wI0, 32, 1);
  wprep_kernel<<<24, 256, 0, stream>>>(Whh0, wH0, 128, 4);
  wprep_kernel<<<24, 256, 0, stream>>>(Whh1, wH1, 128, 4);
  wprep_kernel<<<24, 256, 0, stream>>>(Wih1, wI1, 128, 4);
  xprep_kernel<<<(NNODE * TT * 64 + 255) / 256, 256, 0, stream>>>(x, xb);
  gru2_kernel<<<NBLK, 512, 0, stream>>>(
      xb, wI0, wH0, wI1, wH1, bih0, bhh0, bih1, bhh1, xg);
  graph_kernel<<<NGRAPH, 256, 0, stream>>>(xg, Wq, Wk, Wl, Wr, bsg, Wc, out);
}